// Round 5
// baseline (315.966 us; speedup 1.0000x reference)
//
#include <hip/hip_runtime.h>
#include <hip/hip_bf16.h>
#include <math.h>

typedef __bf16 bf16t;
typedef __bf16 bf8v __attribute__((ext_vector_type(8)));
typedef float  f4v  __attribute__((ext_vector_type(4)));
typedef float  f16v __attribute__((ext_vector_type(16)));
typedef unsigned int u4v __attribute__((ext_vector_type(4)));

#define DD  4
#define FF  64
#define HH  128
#define FIN 129

__device__ __forceinline__ unsigned packbf(float a, float b) {
  unsigned short x = __builtin_bit_cast(unsigned short, (bf16t)a);
  unsigned short y = __builtin_bit_cast(unsigned short, (bf16t)b);
  return (unsigned)x | ((unsigned)y << 16);
}

// ---- weight prep: f32 -> bf16 transpose to [n][k], LDS-tiled ----
// one block per 128x128 matrix: 0-3 w1[d], 4-7 w2[d], 8 w3
__global__ void prep_weights(const float* __restrict__ w1,
                             const float* __restrict__ w2,
                             const float* __restrict__ w3,
                             bf16t* __restrict__ w1t,
                             bf16t* __restrict__ w2t,
                             bf16t* __restrict__ w3t,
                             float* __restrict__ w1last) {
  __shared__ bf16t tile[128 * 65];
  const int mm = blockIdx.x;
  const float* src;
  bf16t* dst;
  if (mm < 4)      { src = w1 + mm * FIN * HH;      dst = w1t + mm * HH * HH; }
  else if (mm < 8) { src = w2 + (mm - 4) * HH * HH; dst = w2t + (mm - 4) * HH * HH; }
  else             { src = w3;                      dst = w3t; }
  const int tid = threadIdx.x;
  for (int h = 0; h < 2; ++h) {
    __syncthreads();
    for (int i = 0; i < 32; ++i) {
      int idx = tid + i * 256;
      int k = idx >> 7, n = idx & 127;
      tile[n * 65 + k] = (bf16t)src[(h * 64 + k) * HH + n];
    }
    __syncthreads();
    for (int i = 0; i < 32; ++i) {
      int idx = tid + i * 256;
      int n = idx >> 6, k = idx & 63;
      dst[n * HH + h * 64 + k] = tile[n * 65 + k];
    }
  }
  if (mm < 4 && tid < HH) w1last[mm * HH + tid] = src[128 * HH + tid];
}

// ---- fully fused, zero-LDS, zero-barrier; 4 independent waves/block, 32 rows/wave ----
__launch_bounds__(256, 2)
__global__ void fourier_mlp(
    const float* __restrict__ cont,   // [N,4]
    const float* __restrict__ freqs,  // [4,64]
    const float* __restrict__ b1,     // [4,128]
    const float* __restrict__ ln1g,
    const float* __restrict__ ln1b,
    const float* __restrict__ b2,
    const float* __restrict__ outg,   // [128]
    const float* __restrict__ outb,
    const float* __restrict__ b3,
    const bf16t* __restrict__ w1t,    // [4][128][128] bf16, [n][k]
    const bf16t* __restrict__ w2t,    // [4][128][128]
    const bf16t* __restrict__ w3t,    // [128][128]
    const float* __restrict__ w1last, // [4][128]
    float* __restrict__ out)          // [N,128] f32
{
  const int lane = threadIdx.x & 63;
  const int wid  = threadIdx.x >> 6;
  const int m    = lane & 31;        // batch-row (or weight-row) index in tile
  const int h5   = lane >> 5;        // K-half selector
  const int rowbase = (blockIdx.x * 4 + wid) * 32;

  // per-lane cont for row rowbase+m, all 4 dims (16B coalesced)
  f4v c4 = *(const f4v*)&cont[(rowbase + m) * DD];

  f16v emb[4];
  #pragma unroll
  for (int nt = 0; nt < 4; ++nt)
    #pragma unroll
    for (int i = 0; i < 16; ++i) emb[nt][i] = 0.0f;

  for (int d = 0; d < DD; ++d) {
    const float cd = c4[d];

    // ---- trig B-frags: ff[kt] holds feat[m][k = kt*16 + h5*8 + j] ----
    // k<64: cos(2*pi*c*f[k]); k>=64: sin(...)  (HW trig in revolutions)
    bf8v ff[8];
    #pragma unroll
    for (int kt2 = 0; kt2 < 4; ++kt2) {
      f4v fa = *(const f4v*)&freqs[d * FF + kt2 * 16 + h5 * 8];
      f4v fb = *(const f4v*)&freqs[d * FF + kt2 * 16 + h5 * 8 + 4];
      #pragma unroll
      for (int j = 0; j < 4; ++j) {
        float t = cd * fa[j]; t -= floorf(t);
        ff[kt2][j]       = (bf16t)__builtin_amdgcn_cosf(t);
        ff[kt2 + 4][j]   = (bf16t)__builtin_amdgcn_sinf(t);
        float t2 = cd * fb[j]; t2 -= floorf(t2);
        ff[kt2][4 + j]     = (bf16t)__builtin_amdgcn_cosf(t2);
        ff[kt2 + 4][4 + j] = (bf16t)__builtin_amdgcn_sinf(t2);
      }
    }

    // ---- GEMM1^T: hT[nt] = w1^T(tile nt) x feat^T ; D: col=m(batch), row=hidden ----
    f16v hT[4];
    #pragma unroll
    for (int nt = 0; nt < 4; ++nt)
      #pragma unroll
      for (int i = 0; i < 16; ++i) hT[nt][i] = 0.0f;

    const bf16t* w1d = w1t + d * HH * HH;
    #pragma unroll
    for (int kt = 0; kt < 8; ++kt)
      #pragma unroll
      for (int nt = 0; nt < 4; ++nt) {
        bf8v wf = *(const bf8v*)&w1d[(nt * 32 + m) * HH + kt * 16 + h5 * 8];
        hT[nt] = __builtin_amdgcn_mfma_f32_32x32x16_bf16(wf, ff[kt], hT[nt], 0, 0, 0);
      }

    // ---- epilogue: +b1 +c*w1last(exact f32), LN over hidden (in-lane 64 + 1 shfl), relu, pack ----
    float s = 0.0f, ss = 0.0f;
    #pragma unroll
    for (int nt = 0; nt < 4; ++nt)
      #pragma unroll
      for (int a = 0; a < 4; ++a) {
        f4v b1v = *(const f4v*)&b1[d * HH + nt * 32 + 8 * a + 4 * h5];
        f4v w1l = *(const f4v*)&w1last[d * HH + nt * 32 + 8 * a + 4 * h5];
        #pragma unroll
        for (int b = 0; b < 4; ++b) {
          float x = hT[nt][4 * a + b] + b1v[b] + cd * w1l[b];
          hT[nt][4 * a + b] = x;
          s += x; ss += x * x;
        }
      }
    s  += __shfl_xor(s, 32);
    ss += __shfl_xor(ss, 32);
    float mu   = s * (1.0f / 128.0f);
    float var  = ss * (1.0f / 128.0f) - mu * mu;
    float rstd = rsqrtf(var + 1e-5f);

    unsigned P[4][8];
    #pragma unroll
    for (int nt = 0; nt < 4; ++nt)
      #pragma unroll
      for (int a = 0; a < 4; ++a) {
        f4v g  = *(const f4v*)&ln1g[d * HH + nt * 32 + 8 * a + 4 * h5];
        f4v bb = *(const f4v*)&ln1b[d * HH + nt * 32 + 8 * a + 4 * h5];
        float y0 = fmaxf((hT[nt][4 * a + 0] - mu) * rstd * g[0] + bb[0], 0.0f);
        float y1 = fmaxf((hT[nt][4 * a + 1] - mu) * rstd * g[1] + bb[1], 0.0f);
        float y2 = fmaxf((hT[nt][4 * a + 2] - mu) * rstd * g[2] + bb[2], 0.0f);
        float y3 = fmaxf((hT[nt][4 * a + 3] - mu) * rstd * g[3] + bb[3], 0.0f);
        P[nt][2 * a]     = packbf(y0, y1);
        P[nt][2 * a + 1] = packbf(y2, y3);
      }

    // ---- C-layout -> B-operand layout: exact lane^32 exchange (2 shfl per kt) ----
    bf8v hf[8];
    #pragma unroll
    for (int kt = 0; kt < 8; ++kt) {
      const int c = 4 * (kt & 1), nt = kt >> 1;
      unsigned own0 = h5 ? P[nt][c + 2] : P[nt][c + 0];
      unsigned own1 = h5 ? P[nt][c + 3] : P[nt][c + 1];
      unsigned x0 = __shfl_xor(h5 ? P[nt][c + 0] : P[nt][c + 2], 32);
      unsigned x1 = __shfl_xor(h5 ? P[nt][c + 1] : P[nt][c + 3], 32);
      u4v t;
      t[0] = h5 ? x0 : own0;
      t[1] = h5 ? x1 : own1;
      t[2] = h5 ? own0 : x0;
      t[3] = h5 ? own1 : x1;
      hf[kt] = __builtin_bit_cast(bf8v, t);
    }

    // ---- GEMM2^T: emb[nt] += w2^T(tile nt) x h^T ----
    const bf16t* w2d = w2t + d * HH * HH;
    #pragma unroll
    for (int kt = 0; kt < 8; ++kt)
      #pragma unroll
      for (int nt = 0; nt < 4; ++nt) {
        bf8v wf = *(const bf8v*)&w2d[(nt * 32 + m) * HH + kt * 16 + h5 * 8];
        emb[nt] = __builtin_amdgcn_mfma_f32_32x32x16_bf16(wf, hf[kt], emb[nt], 0, 0, 0);
      }
    // + b2[d]
    #pragma unroll
    for (int nt = 0; nt < 4; ++nt)
      #pragma unroll
      for (int a = 0; a < 4; ++a) {
        f4v b2v = *(const f4v*)&b2[d * HH + nt * 32 + 8 * a + 4 * h5];
        #pragma unroll
        for (int b = 0; b < 4; ++b) emb[nt][4 * a + b] += b2v[b];
      }
  } // d loop

  // ---- final LN + relu on emb (same per-lane layout), pack, transform ----
  float s = 0.0f, ss = 0.0f;
  #pragma unroll
  for (int nt = 0; nt < 4; ++nt)
    #pragma unroll
    for (int i = 0; i < 16; ++i) { float x = emb[nt][i]; s += x; ss += x * x; }
  s  += __shfl_xor(s, 32);
  ss += __shfl_xor(ss, 32);
  float mu   = s * (1.0f / 128.0f);
  float var  = ss * (1.0f / 128.0f) - mu * mu;
  float rstd = rsqrtf(var + 1e-5f);

  unsigned P[4][8];
  #pragma unroll
  for (int nt = 0; nt < 4; ++nt)
    #pragma unroll
    for (int a = 0; a < 4; ++a) {
      f4v g  = *(const f4v*)&outg[nt * 32 + 8 * a + 4 * h5];
      f4v bb = *(const f4v*)&outb[nt * 32 + 8 * a + 4 * h5];
      float y0 = fmaxf((emb[nt][4 * a + 0] - mu) * rstd * g[0] + bb[0], 0.0f);
      float y1 = fmaxf((emb[nt][4 * a + 1] - mu) * rstd * g[1] + bb[1], 0.0f);
      float y2 = fmaxf((emb[nt][4 * a + 2] - mu) * rstd * g[2] + bb[2], 0.0f);
      float y3 = fmaxf((emb[nt][4 * a + 3] - mu) * rstd * g[3] + bb[3], 0.0f);
      P[nt][2 * a]     = packbf(y0, y1);
      P[nt][2 * a + 1] = packbf(y2, y3);
    }
  bf8v ef[8];
  #pragma unroll
  for (int kt = 0; kt < 8; ++kt) {
    const int c = 4 * (kt & 1), nt = kt >> 1;
    unsigned own0 = h5 ? P[nt][c + 2] : P[nt][c + 0];
    unsigned own1 = h5 ? P[nt][c + 3] : P[nt][c + 1];
    unsigned x0 = __shfl_xor(h5 ? P[nt][c + 0] : P[nt][c + 2], 32);
    unsigned x1 = __shfl_xor(h5 ? P[nt][c + 1] : P[nt][c + 3], 32);
    u4v t;
    t[0] = h5 ? x0 : own0;
    t[1] = h5 ? x1 : own1;
    t[2] = h5 ? own0 : x0;
    t[3] = h5 ? own1 : x1;
    ef[kt] = __builtin_bit_cast(bf8v, t);
  }

  // ---- GEMM3 (normal orientation): out = emb_ln @ w3 ; D: col=out-dim, row=batch ----
  f16v o[4];
  #pragma unroll
  for (int nt = 0; nt < 4; ++nt)
    #pragma unroll
    for (int i = 0; i < 16; ++i) o[nt][i] = 0.0f;

  #pragma unroll
  for (int kt = 0; kt < 8; ++kt)
    #pragma unroll
    for (int nt = 0; nt < 4; ++nt) {
      bf8v wf = *(const bf8v*)&w3t[(nt * 32 + m) * HH + kt * 16 + h5 * 8];
      o[nt] = __builtin_amdgcn_mfma_f32_32x32x16_bf16(ef[kt], wf, o[nt], 0, 0, 0);
    }

  // ---- store: per (nt,reg): 2 rows x 32 consecutive f32 = full 128B segments ----
  #pragma unroll
  for (int nt = 0; nt < 4; ++nt) {
    float b3v = b3[nt * 32 + m];
    #pragma unroll
    for (int reg = 0; reg < 16; ++reg) {
      int row = (reg & 3) + 8 * (reg >> 2) + 4 * h5;
      out[(rowbase + row) * HH + nt * 32 + m] = o[nt][reg] + b3v;
    }
  }
}

extern "C" void kernel_launch(void* const* d_in, const int* in_sizes, int n_in,
                              void* d_out, int out_size, void* d_ws, size_t ws_size,
                              hipStream_t stream) {
  const float* cont  = (const float*)d_in[0];
  const float* freqs = (const float*)d_in[1];
  const float* w1    = (const float*)d_in[2];
  const float* b1    = (const float*)d_in[3];
  const float* ln1g  = (const float*)d_in[4];
  const float* ln1b  = (const float*)d_in[5];
  const float* w2    = (const float*)d_in[6];
  const float* b2    = (const float*)d_in[7];
  const float* outg  = (const float*)d_in[8];
  const float* outb  = (const float*)d_in[9];
  const float* w3    = (const float*)d_in[10];
  const float* b3    = (const float*)d_in[11];
  float* out = (float*)d_out;

  // ws layout: w1t[65536] bf16 | w2t[65536] bf16 | w3t[16384] bf16 | w1last[512] f32
  bf16t* w1t = (bf16t*)d_ws;
  bf16t* w2t = w1t + DD * HH * HH;
  bf16t* w3t = w2t + DD * HH * HH;
  float* w1last = (float*)((char*)d_ws + (2 * DD * HH * HH + HH * HH) * sizeof(bf16t));

  prep_weights<<<9, 256, 0, stream>>>(w1, w2, w3, w1t, w2t, w3t, w1last);

  int n_rows = in_sizes[0] / DD;       // 131072
  int grid = n_rows / 128;             // 1024 blocks x 4 waves x 32 rows
  fourier_mlp<<<grid, 256, 0, stream>>>(
      cont, freqs, b1, ln1g, ln1b, b2, outg, outb, b3,
      w1t, w2t, w3t, w1last, out);
}

// Round 6
// 299.195 us; speedup vs baseline: 1.0561x; 1.0561x over previous
//
#include <hip/hip_runtime.h>
#include <hip/hip_bf16.h>
#include <math.h>

typedef __bf16 bf16t;
typedef __bf16 bf8v __attribute__((ext_vector_type(8)));
typedef float  f4v  __attribute__((ext_vector_type(4)));
typedef float  f16v __attribute__((ext_vector_type(16)));
typedef unsigned int u4v __attribute__((ext_vector_type(4)));

#define DD  4
#define FF  64
#define HH  128
#define FIN 129

__device__ __forceinline__ unsigned packbf(float a, float b) {
  unsigned short x = __builtin_bit_cast(unsigned short, (bf16t)a);
  unsigned short y = __builtin_bit_cast(unsigned short, (bf16t)b);
  return (unsigned)x | ((unsigned)y << 16);
}

// ---- weight prep: f32 -> bf16, emitted in MFMA fragment order ----
// frag layout: chunk c = (nt*8 + kt)*64 + lane ; chunk holds W^T[n][k..k+7]
// with n = nt*32 + (lane&31), k = kt*16 + (lane>>5)*8.
// One block per 128x128 matrix: 0-3 w1[d], 4-7 w2[d], 8 w3.
__global__ void prep_weights(const float* __restrict__ w1,
                             const float* __restrict__ w2,
                             const float* __restrict__ w3,
                             bf16t* __restrict__ w1f,
                             bf16t* __restrict__ w2f,
                             bf16t* __restrict__ w3f,
                             float* __restrict__ w1last) {
  __shared__ bf16t tile[128 * 130];   // [n][k] padded (+2)
  const int mm = blockIdx.x;
  const float* src;
  bf16t* dst;
  if (mm < 4)      { src = w1 + mm * FIN * HH;      dst = w1f + mm * HH * HH; }
  else if (mm < 8) { src = w2 + (mm - 4) * HH * HH; dst = w2f + (mm - 4) * HH * HH; }
  else             { src = w3;                      dst = w3f; }
  const int tid = threadIdx.x;
  // load [k][n] (coalesced in n) -> tile[n][k]
  for (int i = 0; i < 64; ++i) {
    int idx = tid + i * 256;          // 0..16383
    int k = idx >> 7, n = idx & 127;
    tile[n * 130 + k] = (bf16t)src[k * HH + n];
  }
  __syncthreads();
  // emit fragment order, coalesced 16B chunks
  for (int i = 0; i < 8; ++i) {
    int c = tid + i * 256;            // 0..2047
    int nt = c >> 9, kt = (c >> 6) & 7, ln = c & 63;
    int n = nt * 32 + (ln & 31);
    int k = kt * 16 + (ln >> 5) * 8;
    bf8v v;
    #pragma unroll
    for (int j = 0; j < 8; ++j) v[j] = tile[n * 130 + k + j];
    *(bf8v*)&dst[c * 8] = v;
  }
  if (mm < 4 && tid < HH) w1last[mm * HH + tid] = src[128 * HH + tid];
}

// ---- fully fused, zero-barrier; 4 independent waves/block, 32 rows/wave ----
__launch_bounds__(256, 2)
__global__ void fourier_mlp(
    const float* __restrict__ cont,   // [N,4]
    const float* __restrict__ freqs,  // [4,64]
    const float* __restrict__ b1,     // [4,128]
    const float* __restrict__ ln1g,
    const float* __restrict__ ln1b,
    const float* __restrict__ b2,
    const float* __restrict__ outg,   // [128]
    const float* __restrict__ outb,
    const float* __restrict__ b3,
    const bf16t* __restrict__ w1f,    // [4][2048] bf8v fragments
    const bf16t* __restrict__ w2f,    // [4][2048]
    const bf16t* __restrict__ w3f,    // [2048]
    const float* __restrict__ w1last, // [4][128]
    float* __restrict__ out)          // [N,128] f32
{
  __shared__ __align__(16) float so[4 * 32 * HH];  // 64 KB: store-staging, wave-private slabs

  const int lane = threadIdx.x & 63;
  const int wid  = threadIdx.x >> 6;
  const int m    = lane & 31;        // batch-row (or weight-n) index in tile
  const int h5   = lane >> 5;        // K-half selector
  const int rowbase = (blockIdx.x * 4 + wid) * 32;

  // per-lane cont for row rowbase+m, all 4 dims (16B coalesced)
  f4v c4 = *(const f4v*)&cont[(rowbase + m) * DD];

  f16v emb[4];
  #pragma unroll
  for (int nt = 0; nt < 4; ++nt)
    #pragma unroll
    for (int i = 0; i < 16; ++i) emb[nt][i] = 0.0f;

  for (int d = 0; d < DD; ++d) {
    const float cd = c4[d];

    // ---- trig B-frags: ff[kt] holds feat[m][k = kt*16 + h5*8 + j] ----
    // k<64: cos(2*pi*c*f[k]); k>=64: sin(...)  (HW trig in revolutions)
    bf8v ff[8];
    #pragma unroll
    for (int kt2 = 0; kt2 < 4; ++kt2) {
      f4v fa = *(const f4v*)&freqs[d * FF + kt2 * 16 + h5 * 8];
      f4v fb = *(const f4v*)&freqs[d * FF + kt2 * 16 + h5 * 8 + 4];
      #pragma unroll
      for (int j = 0; j < 4; ++j) {
        float t = cd * fa[j]; t -= floorf(t);
        ff[kt2][j]       = (bf16t)__builtin_amdgcn_cosf(t);
        ff[kt2 + 4][j]   = (bf16t)__builtin_amdgcn_sinf(t);
        float t2 = cd * fb[j]; t2 -= floorf(t2);
        ff[kt2][4 + j]     = (bf16t)__builtin_amdgcn_cosf(t2);
        ff[kt2 + 4][4 + j] = (bf16t)__builtin_amdgcn_sinf(t2);
      }
    }

    // ---- GEMM1^T: hT[nt] = w1^T(tile nt) x feat^T ; D: col=m(batch), row=hidden ----
    f16v hT[4];
    #pragma unroll
    for (int nt = 0; nt < 4; ++nt)
      #pragma unroll
      for (int i = 0; i < 16; ++i) hT[nt][i] = 0.0f;

    const bf8v* w1d = (const bf8v*)(w1f + d * HH * HH);
    #pragma unroll
    for (int kt = 0; kt < 8; ++kt)
      #pragma unroll
      for (int nt = 0; nt < 4; ++nt) {
        bf8v wf = w1d[(nt * 8 + kt) * 64 + lane];   // coalesced 1KB/instr
        hT[nt] = __builtin_amdgcn_mfma_f32_32x32x16_bf16(wf, ff[kt], hT[nt], 0, 0, 0);
      }

    // ---- epilogue: +b1 +c*w1last(exact f32), LN over hidden (in-lane 64 + 1 shfl), relu, pack ----
    float s = 0.0f, ss = 0.0f;
    #pragma unroll
    for (int nt = 0; nt < 4; ++nt)
      #pragma unroll
      for (int a = 0; a < 4; ++a) {
        f4v b1v = *(const f4v*)&b1[d * HH + nt * 32 + 8 * a + 4 * h5];
        f4v w1l = *(const f4v*)&w1last[d * HH + nt * 32 + 8 * a + 4 * h5];
        #pragma unroll
        for (int b = 0; b < 4; ++b) {
          float x = hT[nt][4 * a + b] + b1v[b] + cd * w1l[b];
          hT[nt][4 * a + b] = x;
          s += x; ss += x * x;
        }
      }
    s  += __shfl_xor(s, 32);
    ss += __shfl_xor(ss, 32);
    float mu   = s * (1.0f / 128.0f);
    float var  = ss * (1.0f / 128.0f) - mu * mu;
    float rstd = rsqrtf(var + 1e-5f);

    unsigned P[4][8];
    #pragma unroll
    for (int nt = 0; nt < 4; ++nt)
      #pragma unroll
      for (int a = 0; a < 4; ++a) {
        f4v g  = *(const f4v*)&ln1g[d * HH + nt * 32 + 8 * a + 4 * h5];
        f4v bb = *(const f4v*)&ln1b[d * HH + nt * 32 + 8 * a + 4 * h5];
        float y0 = fmaxf((hT[nt][4 * a + 0] - mu) * rstd * g[0] + bb[0], 0.0f);
        float y1 = fmaxf((hT[nt][4 * a + 1] - mu) * rstd * g[1] + bb[1], 0.0f);
        float y2 = fmaxf((hT[nt][4 * a + 2] - mu) * rstd * g[2] + bb[2], 0.0f);
        float y3 = fmaxf((hT[nt][4 * a + 3] - mu) * rstd * g[3] + bb[3], 0.0f);
        P[nt][2 * a]     = packbf(y0, y1);
        P[nt][2 * a + 1] = packbf(y2, y3);
      }

    // ---- C-layout -> B-operand layout: exact lane^32 exchange (verified R5) ----
    bf8v hf[8];
    #pragma unroll
    for (int kt = 0; kt < 8; ++kt) {
      const int c = 4 * (kt & 1), nt = kt >> 1;
      unsigned own0 = h5 ? P[nt][c + 2] : P[nt][c + 0];
      unsigned own1 = h5 ? P[nt][c + 3] : P[nt][c + 1];
      unsigned x0 = __shfl_xor(h5 ? P[nt][c + 0] : P[nt][c + 2], 32);
      unsigned x1 = __shfl_xor(h5 ? P[nt][c + 1] : P[nt][c + 3], 32);
      u4v t;
      t[0] = h5 ? x0 : own0;
      t[1] = h5 ? x1 : own1;
      t[2] = h5 ? own0 : x0;
      t[3] = h5 ? own1 : x1;
      hf[kt] = __builtin_bit_cast(bf8v, t);
    }

    // ---- GEMM2^T: emb[nt] += w2^T(tile nt) x h^T ----
    const bf8v* w2d = (const bf8v*)(w2f + d * HH * HH);
    #pragma unroll
    for (int kt = 0; kt < 8; ++kt)
      #pragma unroll
      for (int nt = 0; nt < 4; ++nt) {
        bf8v wf = w2d[(nt * 8 + kt) * 64 + lane];
        emb[nt] = __builtin_amdgcn_mfma_f32_32x32x16_bf16(wf, hf[kt], emb[nt], 0, 0, 0);
      }
    // + b2[d]
    #pragma unroll
    for (int nt = 0; nt < 4; ++nt)
      #pragma unroll
      for (int a = 0; a < 4; ++a) {
        f4v b2v = *(const f4v*)&b2[d * HH + nt * 32 + 8 * a + 4 * h5];
        #pragma unroll
        for (int b = 0; b < 4; ++b) emb[nt][4 * a + b] += b2v[b];
      }
  } // d loop

  // ---- final LN + relu on emb (same per-lane layout), pack, transform ----
  float s = 0.0f, ss = 0.0f;
  #pragma unroll
  for (int nt = 0; nt < 4; ++nt)
    #pragma unroll
    for (int i = 0; i < 16; ++i) { float x = emb[nt][i]; s += x; ss += x * x; }
  s  += __shfl_xor(s, 32);
  ss += __shfl_xor(ss, 32);
  float mu   = s * (1.0f / 128.0f);
  float var  = ss * (1.0f / 128.0f) - mu * mu;
  float rstd = rsqrtf(var + 1e-5f);

  unsigned P[4][8];
  #pragma unroll
  for (int nt = 0; nt < 4; ++nt)
    #pragma unroll
    for (int a = 0; a < 4; ++a) {
      f4v g  = *(const f4v*)&outg[nt * 32 + 8 * a + 4 * h5];
      f4v bb = *(const f4v*)&outb[nt * 32 + 8 * a + 4 * h5];
      float y0 = fmaxf((emb[nt][4 * a + 0] - mu) * rstd * g[0] + bb[0], 0.0f);
      float y1 = fmaxf((emb[nt][4 * a + 1] - mu) * rstd * g[1] + bb[1], 0.0f);
      float y2 = fmaxf((emb[nt][4 * a + 2] - mu) * rstd * g[2] + bb[2], 0.0f);
      float y3 = fmaxf((emb[nt][4 * a + 3] - mu) * rstd * g[3] + bb[3], 0.0f);
      P[nt][2 * a]     = packbf(y0, y1);
      P[nt][2 * a + 1] = packbf(y2, y3);
    }
  bf8v ef[8];
  #pragma unroll
  for (int kt = 0; kt < 8; ++kt) {
    const int c = 4 * (kt & 1), nt = kt >> 1;
    unsigned own0 = h5 ? P[nt][c + 2] : P[nt][c + 0];
    unsigned own1 = h5 ? P[nt][c + 3] : P[nt][c + 1];
    unsigned x0 = __shfl_xor(h5 ? P[nt][c + 0] : P[nt][c + 2], 32);
    unsigned x1 = __shfl_xor(h5 ? P[nt][c + 1] : P[nt][c + 3], 32);
    u4v t;
    t[0] = h5 ? x0 : own0;
    t[1] = h5 ? x1 : own1;
    t[2] = h5 ? own0 : x0;
    t[3] = h5 ? own1 : x1;
    ef[kt] = __builtin_bit_cast(bf8v, t);
  }

  // ---- GEMM3 (normal orientation): out = emb_ln @ w3 ; D: col=out-dim, row=batch ----
  f16v o[4];
  #pragma unroll
  for (int nt = 0; nt < 4; ++nt)
    #pragma unroll
    for (int i = 0; i < 16; ++i) o[nt][i] = 0.0f;

  const bf8v* w3d = (const bf8v*)w3f;
  #pragma unroll
  for (int kt = 0; kt < 8; ++kt)
    #pragma unroll
    for (int nt = 0; nt < 4; ++nt) {
      bf8v wf = w3d[(nt * 8 + kt) * 64 + lane];
      o[nt] = __builtin_amdgcn_mfma_f32_32x32x16_bf16(ef[kt], wf, o[nt], 0, 0, 0);
    }

  // ---- store: stage C-layout into wave-private LDS slab, then 16 x 1KB coalesced writes ----
  float* sw = so + wid * 32 * HH;
  #pragma unroll
  for (int nt = 0; nt < 4; ++nt) {
    float b3v = b3[nt * 32 + m];
    #pragma unroll
    for (int reg = 0; reg < 16; ++reg) {
      int row = (reg & 3) + 8 * (reg >> 2) + 4 * h5;
      sw[row * HH + nt * 32 + m] = o[nt][reg] + b3v;   // banks 0..31, 2-way: free
    }
  }
  // same-wave LDS RAW: compiler inserts lgkmcnt wait
  float* outw = out + (size_t)rowbase * HH;
  #pragma unroll
  for (int i = 0; i < 16; ++i) {
    f4v v = *(const f4v*)&sw[(i * 64 + lane) * 4];
    *(f4v*)&outw[(i * 64 + lane) * 4] = v;             // 1KB contiguous per instr
  }
}

extern "C" void kernel_launch(void* const* d_in, const int* in_sizes, int n_in,
                              void* d_out, int out_size, void* d_ws, size_t ws_size,
                              hipStream_t stream) {
  const float* cont  = (const float*)d_in[0];
  const float* freqs = (const float*)d_in[1];
  const float* w1    = (const float*)d_in[2];
  const float* b1    = (const float*)d_in[3];
  const float* ln1g  = (const float*)d_in[4];
  const float* ln1b  = (const float*)d_in[5];
  const float* w2    = (const float*)d_in[6];
  const float* b2    = (const float*)d_in[7];
  const float* outg  = (const float*)d_in[8];
  const float* outb  = (const float*)d_in[9];
  const float* w3    = (const float*)d_in[10];
  const float* b3    = (const float*)d_in[11];
  float* out = (float*)d_out;

  // ws layout: w1f[65536] bf16 | w2f[65536] bf16 | w3f[16384] bf16 | w1last[512] f32
  bf16t* w1f = (bf16t*)d_ws;
  bf16t* w2f = w1f + DD * HH * HH;
  bf16t* w3f = w2f + DD * HH * HH;
  float* w1last = (float*)((char*)d_ws + (2 * DD * HH * HH + HH * HH) * sizeof(bf16t));

  prep_weights<<<9, 256, 0, stream>>>(w1, w2, w3, w1f, w2f, w3f, w1last);

  int n_rows = in_sizes[0] / DD;       // 131072
  int grid = n_rows / 128;             // 1024 blocks x 4 waves x 32 rows
  fourier_mlp<<<grid, 256, 0, stream>>>(
      cont, freqs, b1, ln1g, ln1b, b2, outg, outb, b3,
      w1f, w2f, w3f, w1last, out);
}